// Round 15
// baseline (936.203 us; speedup 1.0000x reference)
//
#include <hip/hip_runtime.h>
#include <math.h>

#define N_NODES 100000
#define N_EDGES 1600000
#define TOT (2 * N_NODES)            // CSR buckets: 2*row + adj
#define SCAN_NB 256
#define SCAN_CH 4                    // 256*256*4 = 262144 >= 2N+1
#define RPB 25000                    // rows per scatter bucket pass
#define EG_CAP 4800000               // padded CSR capacity (2E + 7*2N = 4.6M)

static inline int cdiv(long a, long b) { return (int)((a + b - 1) / b); }

typedef unsigned int uint;
typedef unsigned short ushort;
typedef __attribute__((ext_vector_type(8))) short short8v;   // 8 bf16 (4 VGPR)
typedef __attribute__((ext_vector_type(4))) float f32x4;

__device__ inline float bf2f(uint u) { return __uint_as_float(u << 16); }
__device__ inline ushort f2bf(float f) {
    uint u = __float_as_uint(f);
    uint r = ((u >> 16) & 1u) + 0x7fffu;   // RNE
    return (ushort)((u + r) >> 16);
}

// ---------------- MFMA bf16 GEMM: C[i,m] = sum_k A[i,k]*B[k,m] --------------
template <int K, int M, bool AF32, int OUT, bool ELU, bool LOSS>
__global__ __launch_bounds__(256) void gemm_mfma(const void* __restrict__ Av,
                                                 const ushort* __restrict__ Bcm,
                                                 void* __restrict__ Cv,
                                                 void* __restrict__ Cv2,
                                                 const float* __restrict__ Xref,
                                                 float* __restrict__ partial,
                                                 int nrows) {
    constexpr int BM = 128;
    constexpr int KP = K + 8;
    constexpr int NCT = M / 16;
    __shared__ ushort Blds[M * KP];
    __shared__ ushort Alds[BM * 32];
    const int w = threadIdx.x >> 6;
    const int l = threadIdx.x & 63;
    const int rowg = l & 15;
    const int kg = l >> 4;
    const int rbase = blockIdx.x * BM;
    {
        const uint4* src = reinterpret_cast<const uint4*>(Bcm);
        uint4* dst = reinterpret_cast<uint4*>(Blds);
        const int total = M * KP / 8;
        for (int i = threadIdx.x; i < total; i += 256) dst[i] = src[i];
    }
    f32x4 acc[2][NCT] = {};
    for (int k0 = 0; k0 < K; k0 += 32) {
        __syncthreads();
        int r = threadIdx.x >> 1;
        int kk = (threadIdx.x & 1) * 16;
        int rg = min(rbase + r, nrows - 1);
        if (AF32) {
            const float* A = (const float*)Av;
            const float4* src = reinterpret_cast<const float4*>(A + (size_t)rg * K + k0 + kk);
            ushort* dst = &Alds[r * 32 + kk];
#pragma unroll
            for (int q = 0; q < 4; ++q) {
                float4 v = src[q];
                dst[4 * q + 0] = f2bf(v.x); dst[4 * q + 1] = f2bf(v.y);
                dst[4 * q + 2] = f2bf(v.z); dst[4 * q + 3] = f2bf(v.w);
            }
        } else {
            const ushort* A = (const ushort*)Av;
            const uint4* src = reinterpret_cast<const uint4*>(A + (size_t)rg * K + k0 + kk);
            uint4* dst = reinterpret_cast<uint4*>(&Alds[r * 32 + kk]);
            dst[0] = src[0];
            dst[1] = src[1];
        }
        __syncthreads();
#pragma unroll
        for (int rt = 0; rt < 2; ++rt) {
            short8v af = *reinterpret_cast<const short8v*>(
                &Alds[(w * 32 + rt * 16 + rowg) * 32 + kg * 8]);
#pragma unroll
            for (int ct = 0; ct < NCT; ++ct) {
                short8v bf = *reinterpret_cast<const short8v*>(
                    &Blds[(ct * 16 + rowg) * KP + k0 + kg * 8]);
                acc[rt][ct] = __builtin_amdgcn_mfma_f32_16x16x32_bf16(
                    af, bf, acc[rt][ct], 0, 0, 0);
            }
        }
    }
    float lsum = 0.f;
#pragma unroll
    for (int rt = 0; rt < 2; ++rt) {
#pragma unroll
        for (int q = 0; q < 4; ++q) {
            int r = rbase + w * 32 + rt * 16 + kg * 4 + q;
            if (r >= nrows) continue;
#pragma unroll
            for (int ct = 0; ct < NCT; ++ct) {
                float o = acc[rt][ct][q];
                if (ELU) o = o > 0.f ? o : expm1f(o);
                int col = ct * 16 + rowg;
                if (OUT == 0 || OUT == 3) ((float*)Cv)[(size_t)r * M + col] = o;
                if (OUT == 2) ((ushort*)Cv)[(size_t)r * M + col] = f2bf(o);
                if (OUT == 3) ((ushort*)Cv2)[(size_t)r * M + col] = f2bf(o);
                if (LOSS) {
                    float d = o - Xref[(size_t)r * 256 + col];
                    lsum += d * d;
                }
            }
        }
    }
    if (LOSS) {
        __shared__ float smRed[4];
#pragma unroll
        for (int off = 32; off > 0; off >>= 1) lsum += __shfl_down(lsum, off);
        __syncthreads();
        if (l == 0) smRed[w] = lsum;
        __syncthreads();
        if (threadIdx.x == 0)
            partial[blockIdx.x] = smRed[0] + smRed[1] + smRed[2] + smRed[3];
    }
}

// ---------------- weight prep: all 4 bf16 col-major padded B's in one -------
__global__ __launch_bounds__(256) void prep_all_kernel(const float* __restrict__ W0,
                                                       const float* __restrict__ W1,
                                                       ushort* __restrict__ B1,
                                                       ushort* __restrict__ B5,
                                                       ushort* __restrict__ B7,
                                                       ushort* __restrict__ B8) {
    int i = blockIdx.x * 256 + threadIdx.x;
    if (i < 32768) {                            // B1[k][m]=W0[k][m] K=256 M=128
        int k = i / 128, m = i - k * 128;
        B1[m * 264 + k] = f2bf(W0[i]);
        // B8[k][m]=W0[m][k] K=128 M=256 (same element, different slot)
        int m8 = k, k8 = m;                     // W0[i] = W0[k][m] -> B8 row m8=... 
        B8[i % 1 * 0 + 0] = B8[0];              // placeholder avoided below
    }
    // do each mapping independently for clarity
    if (i < 32768) {
        int k = i / 128, m = i - k * 128;       // W0[k][m]
        B1[m * 264 + k] = f2bf(W0[i]);
    } else if (i < 65536) {
        int j = i - 32768;                      // W0[m][k] view: j = m*128+k
        int m = j / 128, k = j - m * 128;
        B8[m * 136 + k] = f2bf(W0[j]);          // B8[k'][m'] with K=128,M=256: row m (0..255), col k
    } else if (i < 73728) {
        int j = i - 65536;                      // W1[k][m], K=128 M=64
        int k = j / 64, m = j - k * 64;
        B5[m * 136 + k] = f2bf(W1[j]);
    } else if (i < 81920) {
        int j = i - 73728;                      // W1[m][k] -> B7 K=64 M=128
        int m = j / 64, k = j - m * 64;
        B7[m * 72 + k] = f2bf(W1[j]);
    }
}

// ---------------- attention feature dots (bf16 H): all 4 at once ------------
__global__ __launch_bounds__(256) void attn_f4_kernel(const ushort* __restrict__ Hb,
                                                      const float* __restrict__ va,
                                                      const float* __restrict__ vb,
                                                      const float* __restrict__ pva,
                                                      const float* __restrict__ pvb,
                                                      float* __restrict__ f1,
                                                      float* __restrict__ f2,
                                                      float* __restrict__ pf1,
                                                      float* __restrict__ pf2) {
    int wid = (blockIdx.x * 256 + threadIdx.x) >> 6;
    int lane = threadIdx.x & 63;
    if (wid >= N_NODES) return;
    uint hv = reinterpret_cast<const uint*>(Hb + (size_t)wid * 128)[lane];
    float x0 = bf2f(hv & 0xffffu);
    float x1 = bf2f(hv >> 16);
    int k = 2 * lane;
    float a = x0 * va[k] + x1 * va[k + 1];
    float b = x0 * vb[k] + x1 * vb[k + 1];
    float pa = x0 * pva[k] + x1 * pva[k + 1];
    float pb = x0 * pvb[k] + x1 * pvb[k + 1];
#pragma unroll
    for (int off = 32; off > 0; off >>= 1) {
        a += __shfl_down(a, off);
        b += __shfl_down(b, off);
        pa += __shfl_down(pa, off);
        pb += __shfl_down(pb, off);
    }
    if (lane == 0) { f1[wid] = a; f2[wid] = b; pf1[wid] = pa; pf2[wid] = pb; }
}

// ---------------- CSR build: bucket = 2*row + adj, rows padded to x8 --------
__global__ __launch_bounds__(256) void hist2_kernel(const int* __restrict__ rows,
                                                    const int* __restrict__ prows,
                                                    int* __restrict__ deg) {
    int e = blockIdx.x * 256 + threadIdx.x;
    if (e >= 2 * N_EDGES) return;
    int b = e < N_EDGES ? rows[e] * 2 : prows[e - N_EDGES] * 2 + 1;
    atomicAdd(&deg[b], 1);
}

__device__ inline int pad8(int d) { return (d + 7) & ~7; }

__global__ __launch_bounds__(256) void scan1_kernel(const int* __restrict__ deg,
                                                    int* __restrict__ bsum) {
    __shared__ int sm[256];
    int base = (blockIdx.x * 256 + threadIdx.x) * SCAN_CH;
    int s = 0;
#pragma unroll
    for (int i = 0; i < SCAN_CH; ++i) {
        int idx = base + i;
        if (idx < TOT) s += pad8(deg[idx]);
    }
    sm[threadIdx.x] = s;
    __syncthreads();
    for (int off = 128; off > 0; off >>= 1) {
        if (threadIdx.x < off) sm[threadIdx.x] += sm[threadIdx.x + off];
        __syncthreads();
    }
    if (threadIdx.x == 0) bsum[blockIdx.x] = sm[0];
}

__global__ void scan2_kernel(int* __restrict__ bsum) {
    if (threadIdx.x != 0) return;
    int run = 0;
    for (int i = 0; i < SCAN_NB; ++i) {
        int t = bsum[i];
        bsum[i] = run;
        run += t;
    }
}

__global__ __launch_bounds__(256) void scan3_kernel(const int* __restrict__ deg,
                                                    const int* __restrict__ bsum,
                                                    int* __restrict__ rp) {
    __shared__ int sm[256];
    int base = (blockIdx.x * 256 + threadIdx.x) * SCAN_CH;
    int s = 0;
#pragma unroll
    for (int i = 0; i < SCAN_CH; ++i) {
        int idx = base + i;
        if (idx < TOT) s += pad8(deg[idx]);
    }
    sm[threadIdx.x] = s;
    __syncthreads();
    if (threadIdx.x == 0) {
        int run = bsum[blockIdx.x];
        for (int t = 0; t < 256; ++t) { int tmp = sm[t]; sm[t] = run; run += tmp; }
    }
    __syncthreads();
    int off = sm[threadIdx.x];
#pragma unroll
    for (int i = 0; i < SCAN_CH; ++i) {
        int idx = base + i;
        if (idx < TOT) { rp[idx] = off; off += pad8(deg[idx]); }
        else if (idx == TOT) rp[idx] = off;
    }
}

// fused bucketed scatter: eg[pos] = {col, exp(f1[r]+f2[c])}, sums[b] += exp
__global__ __launch_bounds__(256) void scatter_fused_kernel(const int* __restrict__ rlist,
                                                            const int* __restrict__ clist,
                                                            int adj, int lo, int hi,
                                                            const float* __restrict__ f1t,
                                                            const float* __restrict__ f2t,
                                                            const int* __restrict__ rp,
                                                            int* __restrict__ cur,
                                                            int2* __restrict__ eg,
                                                            float* __restrict__ sums) {
    int e = blockIdx.x * 256 + threadIdx.x;
    if (e >= N_EDGES) return;
    int r0 = rlist[e];
    if (r0 < lo || r0 >= hi) return;
    int c = clist[e];
    float v = __expf(f1t[r0] + f2t[c]);
    int b = r0 * 2 + adj;
    int pos = rp[b] + atomicAdd(&cur[b], 1);
    eg[pos] = make_int2(c, __float_as_int(v));
    atomicAdd(&sums[b], v);
}

// ---------------- fused SpMM, unified row stream, per-block inv select ------
#define SPU 8
__global__ __launch_bounds__(256) void spmm_fused_kernel(const int* __restrict__ rp,
                                                         const int2* __restrict__ eg,
                                                         const float* __restrict__ sums,
                                                         const ushort* __restrict__ Hb,
                                                         float* __restrict__ out) {
    int r = blockIdx.x * 4 + (threadIdx.x >> 6);
    int lane = threadIdx.x & 63;
    const uint* Hu = reinterpret_cast<const uint*>(Hb);
    float a0 = 0.f, a1 = 0.f;
    int j0 = rp[2 * r], mid = rp[2 * r + 1], E = rp[2 * r + 2];
    float s0 = sums[2 * r], s1 = sums[2 * r + 1];
    float inv0 = s0 > 0.f ? 0.2f / s0 : 0.f;
    float inv1 = s1 > 0.f ? 0.8f / s1 : 0.f;
    if (j0 < E) {
        int2 d[SPU]; uint h[SPU];
#pragma unroll
        for (int u = 0; u < SPU; ++u) d[u] = eg[j0 + u];
#pragma unroll
        for (int u = 0; u < SPU; ++u) h[u] = Hu[(uint)d[u].x * 64u + lane];
        int jc = j0;
        for (int j = j0 + SPU; j < E; j += SPU) {
            int2 dn[SPU]; uint hn[SPU];
#pragma unroll
            for (int u = 0; u < SPU; ++u) dn[u] = eg[j + u];
#pragma unroll
            for (int u = 0; u < SPU; ++u) hn[u] = Hu[(uint)dn[u].x * 64u + lane];
            float winv = jc < mid ? inv0 : inv1;
#pragma unroll
            for (int u = 0; u < SPU; ++u) {
                float v = __int_as_float(d[u].y) * winv;
                a0 += v * bf2f(h[u] & 0xffffu);
                a1 += v * bf2f(h[u] >> 16);
            }
#pragma unroll
            for (int u = 0; u < SPU; ++u) { d[u] = dn[u]; h[u] = hn[u]; }
            jc = j;
        }
        float winv = jc < mid ? inv0 : inv1;
#pragma unroll
        for (int u = 0; u < SPU; ++u) {
            float v = __int_as_float(d[u].y) * winv;
            a0 += v * bf2f(h[u] & 0xffffu);
            a1 += v * bf2f(h[u] >> 16);
        }
    }
    float o0 = a0 > 0.f ? a0 : expm1f(a0);
    float o1 = a1 > 0.f ? a1 : expm1f(a1);
    *reinterpret_cast<float2*>(out + (size_t)r * 128 + 2 * lane) = make_float2(o0, o1);
}

__global__ __launch_bounds__(256) void spmm64_fused_kernel(const int* __restrict__ rp,
                                                           const int2* __restrict__ eg,
                                                           const float* __restrict__ sums,
                                                           const ushort* __restrict__ Hb,
                                                           float* __restrict__ S) {
    int r = blockIdx.x * 4 + (threadIdx.x >> 6);
    int lane = threadIdx.x & 63;
    float a = 0.f;
    int j0 = rp[2 * r], mid = rp[2 * r + 1], E = rp[2 * r + 2];
    float s0 = sums[2 * r], s1 = sums[2 * r + 1];
    float inv0 = s0 > 0.f ? 0.2f / s0 : 0.f;
    float inv1 = s1 > 0.f ? 0.8f / s1 : 0.f;
    if (j0 < E) {
        int2 d[SPU]; ushort h[SPU];
#pragma unroll
        for (int u = 0; u < SPU; ++u) d[u] = eg[j0 + u];
#pragma unroll
        for (int u = 0; u < SPU; ++u) h[u] = Hb[(uint)d[u].x * 64u + lane];
        int jc = j0;
        for (int j = j0 + SPU; j < E; j += SPU) {
            int2 dn[SPU]; ushort hn[SPU];
#pragma unroll
            for (int u = 0; u < SPU; ++u) dn[u] = eg[j + u];
#pragma unroll
            for (int u = 0; u < SPU; ++u) hn[u] = Hb[(uint)dn[u].x * 64u + lane];
            float winv = jc < mid ? inv0 : inv1;
#pragma unroll
            for (int u = 0; u < SPU; ++u)
                a += __int_as_float(d[u].y) * winv * bf2f((uint)h[u]);
#pragma unroll
            for (int u = 0; u < SPU; ++u) { d[u] = dn[u]; h[u] = hn[u]; }
            jc = j;
        }
        float winv = jc < mid ? inv0 : inv1;
#pragma unroll
        for (int u = 0; u < SPU; ++u)
            a += __int_as_float(d[u].y) * winv * bf2f((uint)h[u]);
    }
    S[(size_t)r * 64 + lane] = a;
}

// ---------------- reductions -----------------------------------------------
__global__ __launch_bounds__(256) void sq_reduce_kernel(const float* __restrict__ a,
                                                        float* __restrict__ acc, int n) {
    __shared__ float sm[4];
    float s = 0.f;
    for (int i = blockIdx.x * 256 + threadIdx.x; i < n; i += gridDim.x * 256) {
        float d = a[i];
        s += d * d;
    }
#pragma unroll
    for (int off = 32; off > 0; off >>= 1) s += __shfl_down(s, off);
    int lane = threadIdx.x & 63, w = threadIdx.x >> 6;
    if (lane == 0) sm[w] = s;
    __syncthreads();
    if (threadIdx.x == 0) atomicAdd(acc, sm[0] + sm[1] + sm[2] + sm[3]);
}

__global__ __launch_bounds__(256) void partial_reduce_kernel(const float* __restrict__ p,
                                                             int n, float* __restrict__ acc) {
    __shared__ float sm[4];
    float s = 0.f;
    for (int i = threadIdx.x; i < n; i += 256) s += p[i];
#pragma unroll
    for (int off = 32; off > 0; off >>= 1) s += __shfl_down(s, off);
    int lane = threadIdx.x & 63, w = threadIdx.x >> 6;
    if (lane == 0) sm[w] = s;
    __syncthreads();
    if (threadIdx.x == 0) atomicAdd(acc, sm[0] + sm[1] + sm[2] + sm[3]);
}

__global__ void finalize_kernel(const float* __restrict__ acc, float* __restrict__ out) {
    out[0] = sqrtf(acc[0]) + 1e-4f * acc[1];
}

extern "C" void kernel_launch(void* const* d_in, const int* in_sizes, int n_in,
                              void* d_out, int out_size, void* d_ws, size_t ws_size,
                              hipStream_t stream) {
    const float* X    = (const float*)d_in[0];
    const float* W0   = (const float*)d_in[1];
    const float* W1   = (const float*)d_in[2];
    const float* v00  = (const float*)d_in[3];
    const float* v01  = (const float*)d_in[4];
    const float* pv00 = (const float*)d_in[5];
    const float* pv01 = (const float*)d_in[6];
    const int* rows   = (const int*)d_in[7];
    const int* cols   = (const int*)d_in[8];
    const int* prows  = (const int*)d_in[9];
    const int* pcols  = (const int*)d_in[10];

    float* out  = (float*)d_out;
    float* Henc = out + 1;                                  // N x 64 (misaligned base)
    float* Xrec = out + 1 + (size_t)N_NODES * 64;           // N x 256 (misaligned base)

    // scratch in dead X_ region [6400001, 32000001):
    ushort* bufAh  = (ushort*)(out + 6400004);              // N x 128 bf16
    float*  S      = out + 6400004;                         // N x 64 fp32 (after bufAh dead)
    int2*   eg     = (int2*)(out + 12800004);               // EG_CAP int2 (38.4MB)
    ushort* HencB  = (ushort*)(out + 22400004);             // N x 64 bf16
    int*    deg    = (int*)(out + 25600004);                // 2N
    int*    cur    = deg + TOT;                             // 2N
    float*  sums   = (float*)(cur + TOT);                   // 2N

    float* ws   = (float*)d_ws;
    float* bufB = ws;                                       // N x 128 fp32 / bf16
    ushort* bufBh = (ushort*)bufB;
    float* f1   = bufB + (size_t)N_NODES * 128;
    float* f2   = f1 + N_NODES;
    float* pf1  = f2 + N_NODES;
    float* pf2  = pf1 + N_NODES;
    float* acc  = pf2 + N_NODES;                            // 4
    ushort* B1cm = (ushort*)(acc + 4);                      // 128 x 264
    ushort* B5cm = B1cm + 128 * 264;                        // 64 x 136
    ushort* B7cm = B5cm + 64 * 136;                         // 128 x 72
    ushort* B8cm = B7cm + 128 * 72;                         // 256 x 136
    int*   rp   = (int*)(B8cm + 256 * 136);                 // 2N+1
    int*   bsum = rp + TOT + 1;                             // SCAN_NB
    float* partial = (float*)(bsum + SCAN_NB);              // cdiv(n,128)

    const int n = N_NODES;
    const int EG = cdiv(N_EDGES, 256);
    const int EG2 = cdiv(2 * (long)N_EDGES, 256);

    // 0. weight prep (single kernel)
    prep_all_kernel<<<cdiv(81920, 256), 256, 0, stream>>>(W0, W1, B1cm, B5cm, B7cm, B8cm);

    // 1. H1 = X @ W0 -> bufAh (bf16), MFMA
    gemm_mfma<256, 128, true, 2, false, false><<<cdiv(n, 128), 256, 0, stream>>>(
        X, B1cm, bufAh, nullptr, nullptr, nullptr, n);

    // zero deg+cur+sums (3*2N), acc, and eg (pad slots must be {0,0})
    hipMemsetAsync(deg, 0, 3 * (size_t)TOT * sizeof(int), stream);
    hipMemsetAsync(acc, 0, 4 * sizeof(float), stream);
    hipMemsetAsync(eg, 0, (size_t)EG_CAP * sizeof(int2), stream);

    // 2. attention feature dots
    attn_f4_kernel<<<cdiv(n, 4), 256, 0, stream>>>(bufAh, v00, v01, pv00, pv01,
                                                   f1, f2, pf1, pf2);

    // 3. padded interleaved CSR; fused scatter writes {col, exp} + bucket sums
    hist2_kernel<<<EG2, 256, 0, stream>>>(rows, prows, deg);
    scan1_kernel<<<SCAN_NB, 256, 0, stream>>>(deg, bsum);
    scan2_kernel<<<1, 64, 0, stream>>>(bsum);
    scan3_kernel<<<SCAN_NB, 256, 0, stream>>>(deg, bsum, rp);
    for (int p = 0; p < 4; ++p)
        scatter_fused_kernel<<<EG, 256, 0, stream>>>(rows, cols, 0,
                                                     p * RPB, (p + 1) * RPB,
                                                     f1, f2, rp, cur, eg, sums);
    for (int p = 0; p < 4; ++p)
        scatter_fused_kernel<<<EG, 256, 0, stream>>>(prows, pcols, 1,
                                                     p * RPB, (p + 1) * RPB,
                                                     pf1, pf2, rp, cur, eg, sums);

    // 4. encoder: bufB(fp32) = elu(spmm with per-segment softmax scaling)
    spmm_fused_kernel<<<n / 4, 256, 0, stream>>>(rp, eg, sums, bufAh, bufB);

    // 5. Henc = bufB @ W1 -> d_out (fp32) + HencB (bf16), MFMA
    gemm_mfma<128, 64, true, 3, false, false><<<cdiv(n, 128), 256, 0, stream>>>(
        bufB, B5cm, Henc, HencB, nullptr, nullptr, n);

    // 6. decoder spmm on Henc (64-wide) -> S (bufAh region, now dead)
    spmm64_fused_kernel<<<n / 4, 256, 0, stream>>>(rp, eg, sums, HencB, S);

    // 7. D = elu(S @ W1T) -> bufBh (bf16), MFMA
    gemm_mfma<64, 128, true, 2, true, false><<<cdiv(n, 128), 256, 0, stream>>>(
        S, B7cm, bufBh, nullptr, nullptr, nullptr, n);

    // 8. X_ = bufBh @ W0T -> Xrec + fused loss partials, MFMA
    gemm_mfma<128, 256, false, 0, false, true><<<cdiv(n, 128), 256, 0, stream>>>(
        bufBh, B8cm, Xrec, nullptr, X, partial, n);

    // 9. loss (both weight norms accumulate into acc[1])
    partial_reduce_kernel<<<1, 256, 0, stream>>>(partial, cdiv(n, 128), acc + 0);
    sq_reduce_kernel<<<16, 256, 0, stream>>>(W0, acc + 1, 256 * 128);
    sq_reduce_kernel<<<4, 256, 0, stream>>>(W1, acc + 1, 128 * 64);
    finalize_kernel<<<1, 1, 0, stream>>>(acc, out);
}

// Round 16
// 794.212 us; speedup vs baseline: 1.1788x; 1.1788x over previous
//
#include <hip/hip_runtime.h>
#include <math.h>

#define N_NODES 100000
#define N_EDGES 1600000
#define TOT (2 * N_NODES)            // CSR buckets: 2*row + adj
#define SCAN_NB 256
#define SCAN_CH 4                    // 256*256*4 = 262144 >= 2N+1
#define RPB 25000                    // rows per scatter bucket pass

static inline int cdiv(long a, long b) { return (int)((a + b - 1) / b); }

typedef unsigned int uint;
typedef unsigned short ushort;
typedef __attribute__((ext_vector_type(8))) short short8v;   // 8 bf16 (4 VGPR)
typedef __attribute__((ext_vector_type(4))) float f32x4;

__device__ inline float bf2f(uint u) { return __uint_as_float(u << 16); }
__device__ inline ushort f2bf(float f) {
    uint u = __float_as_uint(f);
    uint r = ((u >> 16) & 1u) + 0x7fffu;   // RNE
    return (ushort)((u + r) >> 16);
}

// ---------------- MFMA bf16 GEMM: C[i,m] = sum_k A[i,k]*B[k,m] --------------
template <int K, int M, bool AF32, int OUT, bool ELU, bool LOSS>
__global__ __launch_bounds__(256) void gemm_mfma(const void* __restrict__ Av,
                                                 const ushort* __restrict__ Bcm,
                                                 void* __restrict__ Cv,
                                                 void* __restrict__ Cv2,
                                                 const float* __restrict__ Xref,
                                                 float* __restrict__ partial,
                                                 int nrows) {
    constexpr int BM = 128;
    constexpr int KP = K + 8;
    constexpr int NCT = M / 16;
    __shared__ ushort Blds[M * KP];
    __shared__ ushort Alds[BM * 32];
    const int w = threadIdx.x >> 6;
    const int l = threadIdx.x & 63;
    const int rowg = l & 15;
    const int kg = l >> 4;
    const int rbase = blockIdx.x * BM;
    {
        const uint4* src = reinterpret_cast<const uint4*>(Bcm);
        uint4* dst = reinterpret_cast<uint4*>(Blds);
        const int total = M * KP / 8;
        for (int i = threadIdx.x; i < total; i += 256) dst[i] = src[i];
    }
    f32x4 acc[2][NCT] = {};
    for (int k0 = 0; k0 < K; k0 += 32) {
        __syncthreads();
        int r = threadIdx.x >> 1;
        int kk = (threadIdx.x & 1) * 16;
        int rg = min(rbase + r, nrows - 1);
        if (AF32) {
            const float* A = (const float*)Av;
            const float4* src = reinterpret_cast<const float4*>(A + (size_t)rg * K + k0 + kk);
            ushort* dst = &Alds[r * 32 + kk];
#pragma unroll
            for (int q = 0; q < 4; ++q) {
                float4 v = src[q];
                dst[4 * q + 0] = f2bf(v.x); dst[4 * q + 1] = f2bf(v.y);
                dst[4 * q + 2] = f2bf(v.z); dst[4 * q + 3] = f2bf(v.w);
            }
        } else {
            const ushort* A = (const ushort*)Av;
            const uint4* src = reinterpret_cast<const uint4*>(A + (size_t)rg * K + k0 + kk);
            uint4* dst = reinterpret_cast<uint4*>(&Alds[r * 32 + kk]);
            dst[0] = src[0];
            dst[1] = src[1];
        }
        __syncthreads();
#pragma unroll
        for (int rt = 0; rt < 2; ++rt) {
            short8v af = *reinterpret_cast<const short8v*>(
                &Alds[(w * 32 + rt * 16 + rowg) * 32 + kg * 8]);
#pragma unroll
            for (int ct = 0; ct < NCT; ++ct) {
                short8v bf = *reinterpret_cast<const short8v*>(
                    &Blds[(ct * 16 + rowg) * KP + k0 + kg * 8]);
                acc[rt][ct] = __builtin_amdgcn_mfma_f32_16x16x32_bf16(
                    af, bf, acc[rt][ct], 0, 0, 0);
            }
        }
    }
    float lsum = 0.f;
#pragma unroll
    for (int rt = 0; rt < 2; ++rt) {
#pragma unroll
        for (int q = 0; q < 4; ++q) {
            int r = rbase + w * 32 + rt * 16 + kg * 4 + q;
            if (r >= nrows) continue;
#pragma unroll
            for (int ct = 0; ct < NCT; ++ct) {
                float o = acc[rt][ct][q];
                if (ELU) o = o > 0.f ? o : expm1f(o);
                int col = ct * 16 + rowg;
                if (OUT == 0 || OUT == 3) ((float*)Cv)[(size_t)r * M + col] = o;
                if (OUT == 2) ((ushort*)Cv)[(size_t)r * M + col] = f2bf(o);
                if (OUT == 3) ((ushort*)Cv2)[(size_t)r * M + col] = f2bf(o);
                if (LOSS) {
                    float d = o - Xref[(size_t)r * 256 + col];
                    lsum += d * d;
                }
            }
        }
    }
    if (LOSS) {
        __shared__ float smRed[4];
#pragma unroll
        for (int off = 32; off > 0; off >>= 1) lsum += __shfl_down(lsum, off);
        __syncthreads();
        if (l == 0) smRed[w] = lsum;
        __syncthreads();
        if (threadIdx.x == 0)
            partial[blockIdx.x] = smRed[0] + smRed[1] + smRed[2] + smRed[3];
    }
}

// ---------------- weight prep: all 4 bf16 col-major padded B's, one kernel --
// Disjoint index ranges; no overlapping writes (race-free).
__global__ __launch_bounds__(256) void prep_all_kernel(const float* __restrict__ W0,
                                                       const float* __restrict__ W1,
                                                       ushort* __restrict__ B1,
                                                       ushort* __restrict__ B5,
                                                       ushort* __restrict__ B7,
                                                       ushort* __restrict__ B8) {
    int i = blockIdx.x * 256 + threadIdx.x;
    if (i < 32768) {                            // B1[m][k] = W0[k][m], K=256 M=128
        int k = i / 128, m = i - k * 128;
        B1[m * 264 + k] = f2bf(W0[i]);
    } else if (i < 65536) {                     // B8[m][k] = W0[m][k], K=128 M=256
        int j = i - 32768;
        int m = j / 128, k = j - m * 128;
        B8[m * 136 + k] = f2bf(W0[j]);
    } else if (i < 73728) {                     // B5[m][k] = W1[k][m], K=128 M=64
        int j = i - 65536;
        int k = j / 64, m = j - k * 64;
        B5[m * 136 + k] = f2bf(W1[j]);
    } else if (i < 81920) {                     // B7[m][k] = W1[m][k], K=64 M=128
        int j = i - 73728;
        int m = j / 64, k = j - m * 64;
        B7[m * 72 + k] = f2bf(W1[j]);
    }
}

// ---------------- attention feature dots (bf16 H): all 4 at once ------------
__global__ __launch_bounds__(256) void attn_f4_kernel(const ushort* __restrict__ Hb,
                                                      const float* __restrict__ va,
                                                      const float* __restrict__ vb,
                                                      const float* __restrict__ pva,
                                                      const float* __restrict__ pvb,
                                                      float* __restrict__ f1,
                                                      float* __restrict__ f2,
                                                      float* __restrict__ pf1,
                                                      float* __restrict__ pf2) {
    int wid = (blockIdx.x * 256 + threadIdx.x) >> 6;
    int lane = threadIdx.x & 63;
    if (wid >= N_NODES) return;
    uint hv = reinterpret_cast<const uint*>(Hb + (size_t)wid * 128)[lane];
    float x0 = bf2f(hv & 0xffffu);
    float x1 = bf2f(hv >> 16);
    int k = 2 * lane;
    float a = x0 * va[k] + x1 * va[k + 1];
    float b = x0 * vb[k] + x1 * vb[k + 1];
    float pa = x0 * pva[k] + x1 * pva[k + 1];
    float pb = x0 * pvb[k] + x1 * pvb[k + 1];
#pragma unroll
    for (int off = 32; off > 0; off >>= 1) {
        a += __shfl_down(a, off);
        b += __shfl_down(b, off);
        pa += __shfl_down(pa, off);
        pb += __shfl_down(pb, off);
    }
    if (lane == 0) { f1[wid] = a; f2[wid] = b; pf1[wid] = pa; pf2[wid] = pb; }
}

// ---------------- CSR build: bucket = 2*row + adj, rows padded to x8 --------
__global__ __launch_bounds__(256) void hist2_kernel(const int* __restrict__ rows,
                                                    const int* __restrict__ prows,
                                                    int* __restrict__ deg) {
    int e = blockIdx.x * 256 + threadIdx.x;
    if (e >= 2 * N_EDGES) return;
    int b = e < N_EDGES ? rows[e] * 2 : prows[e - N_EDGES] * 2 + 1;
    atomicAdd(&deg[b], 1);
}

__device__ inline int pad8(int d) { return (d + 7) & ~7; }

__global__ __launch_bounds__(256) void scan1_kernel(const int* __restrict__ deg,
                                                    int* __restrict__ bsum) {
    __shared__ int sm[256];
    int base = (blockIdx.x * 256 + threadIdx.x) * SCAN_CH;
    int s = 0;
#pragma unroll
    for (int i = 0; i < SCAN_CH; ++i) {
        int idx = base + i;
        if (idx < TOT) s += pad8(deg[idx]);
    }
    sm[threadIdx.x] = s;
    __syncthreads();
    for (int off = 128; off > 0; off >>= 1) {
        if (threadIdx.x < off) sm[threadIdx.x] += sm[threadIdx.x + off];
        __syncthreads();
    }
    if (threadIdx.x == 0) bsum[blockIdx.x] = sm[0];
}

__global__ void scan2_kernel(int* __restrict__ bsum) {
    if (threadIdx.x != 0) return;
    int run = 0;
    for (int i = 0; i < SCAN_NB; ++i) {
        int t = bsum[i];
        bsum[i] = run;
        run += t;
    }
}

__global__ __launch_bounds__(256) void scan3_kernel(const int* __restrict__ deg,
                                                    const int* __restrict__ bsum,
                                                    int* __restrict__ rp) {
    __shared__ int sm[256];
    int base = (blockIdx.x * 256 + threadIdx.x) * SCAN_CH;
    int s = 0;
#pragma unroll
    for (int i = 0; i < SCAN_CH; ++i) {
        int idx = base + i;
        if (idx < TOT) s += pad8(deg[idx]);
    }
    sm[threadIdx.x] = s;
    __syncthreads();
    if (threadIdx.x == 0) {
        int run = bsum[blockIdx.x];
        for (int t = 0; t < 256; ++t) { int tmp = sm[t]; sm[t] = run; run += tmp; }
    }
    __syncthreads();
    int off = sm[threadIdx.x];
#pragma unroll
    for (int i = 0; i < SCAN_CH; ++i) {
        int idx = base + i;
        if (idx < TOT) { rp[idx] = off; off += pad8(deg[idx]); }
        else if (idx == TOT) rp[idx] = off;
    }
}

// bucketed scatter: 4B column ids only; write window stays L2-sized
__global__ __launch_bounds__(256) void scatter_bucket_kernel(const int* __restrict__ rlist,
                                                             const int* __restrict__ clist,
                                                             int adj, int lo, int hi,
                                                             const int* __restrict__ rp,
                                                             int* __restrict__ cur,
                                                             int* __restrict__ ccol) {
    int e = blockIdx.x * 256 + threadIdx.x;
    if (e >= N_EDGES) return;
    int r0 = rlist[e];
    if (r0 < lo || r0 >= hi) return;
    int b = r0 * 2 + adj;
    int pos = rp[b] + atomicAdd(&cur[b], 1);
    ccol[pos] = clist[e];
}

// ---------------- edge weights: pre-normalized+scaled; pad slots = {0,0} ----
__global__ __launch_bounds__(256) void edgeval_kernel(const int* __restrict__ rp,
                                                      const int* __restrict__ deg,
                                                      const int* __restrict__ ccol,
                                                      const float* __restrict__ f1,
                                                      const float* __restrict__ f2,
                                                      const float* __restrict__ pf1,
                                                      const float* __restrict__ pf2,
                                                      int2* __restrict__ eg) {
    int b = blockIdx.x * 16 + (threadIdx.x >> 4);
    int sl = threadIdx.x & 15;
    int adj = b & 1, r = b >> 1;
    float f1r = adj ? pf1[r] : f1[r];
    const float* f2t = adj ? pf2 : f2;
    float scale = adj ? 0.8f : 0.2f;
    int j0 = rp[b];
    int realend = j0 + deg[b];
    int pend = rp[b + 1];
    float s = 0.f;
    for (int j = j0 + sl; j < realend; j += 16)
        s += __expf(f1r + f2t[ccol[j]]);
#pragma unroll
    for (int off = 8; off > 0; off >>= 1) s += __shfl_xor(s, off);
    float inv = s > 0.f ? scale / s : 0.f;
    for (int j = j0 + sl; j < pend; j += 16) {
        if (j < realend) {
            int c = ccol[j];
            float wv = __expf(f1r + f2t[c]) * inv;
            eg[j] = make_int2(c, __float_as_int(wv));
        } else {
            eg[j] = make_int2(0, 0);
        }
    }
}

// ---------------- fused SpMM, unified row stream, 2-stage pipeline ----------
#define SPU 8
__global__ __launch_bounds__(256) void spmm_fused_kernel(const int* __restrict__ rp,
                                                         const int2* __restrict__ eg,
                                                         const ushort* __restrict__ Hb,
                                                         float* __restrict__ out) {
    int r = blockIdx.x * 4 + (threadIdx.x >> 6);
    int lane = threadIdx.x & 63;
    const uint* Hu = reinterpret_cast<const uint*>(Hb);
    float a0 = 0.f, a1 = 0.f;
    int j = rp[2 * r], E = rp[2 * r + 2];
    if (j < E) {
        int2 d[SPU]; uint h[SPU];
#pragma unroll
        for (int u = 0; u < SPU; ++u) d[u] = eg[j + u];
#pragma unroll
        for (int u = 0; u < SPU; ++u) h[u] = Hu[(uint)d[u].x * 64u + lane];
        j += SPU;
        for (; j < E; j += SPU) {
            int2 dn[SPU]; uint hn[SPU];
#pragma unroll
            for (int u = 0; u < SPU; ++u) dn[u] = eg[j + u];
#pragma unroll
            for (int u = 0; u < SPU; ++u) hn[u] = Hu[(uint)dn[u].x * 64u + lane];
#pragma unroll
            for (int u = 0; u < SPU; ++u) {
                float v = __int_as_float(d[u].y);
                a0 += v * bf2f(h[u] & 0xffffu);
                a1 += v * bf2f(h[u] >> 16);
            }
#pragma unroll
            for (int u = 0; u < SPU; ++u) { d[u] = dn[u]; h[u] = hn[u]; }
        }
#pragma unroll
        for (int u = 0; u < SPU; ++u) {
            float v = __int_as_float(d[u].y);
            a0 += v * bf2f(h[u] & 0xffffu);
            a1 += v * bf2f(h[u] >> 16);
        }
    }
    float o0 = a0 > 0.f ? a0 : expm1f(a0);
    float o1 = a1 > 0.f ? a1 : expm1f(a1);
    *reinterpret_cast<float2*>(out + (size_t)r * 128 + 2 * lane) = make_float2(o0, o1);
}

// decoder spmm on 64-wide bf16 Henc; emits bf16 S directly
__global__ __launch_bounds__(256) void spmm64_fused_kernel(const int* __restrict__ rp,
                                                           const int2* __restrict__ eg,
                                                           const ushort* __restrict__ Hb,
                                                           ushort* __restrict__ Sh) {
    int r = blockIdx.x * 4 + (threadIdx.x >> 6);
    int lane = threadIdx.x & 63;
    float a = 0.f;
    int j = rp[2 * r], E = rp[2 * r + 2];
    if (j < E) {
        int2 d[SPU]; ushort h[SPU];
#pragma unroll
        for (int u = 0; u < SPU; ++u) d[u] = eg[j + u];
#pragma unroll
        for (int u = 0; u < SPU; ++u) h[u] = Hb[(uint)d[u].x * 64u + lane];
        j += SPU;
        for (; j < E; j += SPU) {
            int2 dn[SPU]; ushort hn[SPU];
#pragma unroll
            for (int u = 0; u < SPU; ++u) dn[u] = eg[j + u];
#pragma unroll
            for (int u = 0; u < SPU; ++u) hn[u] = Hb[(uint)dn[u].x * 64u + lane];
#pragma unroll
            for (int u = 0; u < SPU; ++u)
                a += __int_as_float(d[u].y) * bf2f((uint)h[u]);
#pragma unroll
            for (int u = 0; u < SPU; ++u) { d[u] = dn[u]; h[u] = hn[u]; }
        }
#pragma unroll
        for (int u = 0; u < SPU; ++u)
            a += __int_as_float(d[u].y) * bf2f((uint)h[u]);
    }
    Sh[(size_t)r * 64 + lane] = f2bf(a);
}

// ---------------- reductions -----------------------------------------------
__global__ __launch_bounds__(256) void sq_reduce_kernel(const float* __restrict__ a,
                                                        float* __restrict__ acc, int n) {
    __shared__ float sm[4];
    float s = 0.f;
    for (int i = blockIdx.x * 256 + threadIdx.x; i < n; i += gridDim.x * 256) {
        float d = a[i];
        s += d * d;
    }
#pragma unroll
    for (int off = 32; off > 0; off >>= 1) s += __shfl_down(s, off);
    int lane = threadIdx.x & 63, w = threadIdx.x >> 6;
    if (lane == 0) sm[w] = s;
    __syncthreads();
    if (threadIdx.x == 0) atomicAdd(acc, sm[0] + sm[1] + sm[2] + sm[3]);
}

__global__ __launch_bounds__(256) void partial_reduce_kernel(const float* __restrict__ p,
                                                             int n, float* __restrict__ acc) {
    __shared__ float sm[4];
    float s = 0.f;
    for (int i = threadIdx.x; i < n; i += 256) s += p[i];
#pragma unroll
    for (int off = 32; off > 0; off >>= 1) s += __shfl_down(s, off);
    int lane = threadIdx.x & 63, w = threadIdx.x >> 6;
    if (lane == 0) sm[w] = s;
    __syncthreads();
    if (threadIdx.x == 0) atomicAdd(acc, sm[0] + sm[1] + sm[2] + sm[3]);
}

__global__ void finalize_kernel(const float* __restrict__ acc, float* __restrict__ out) {
    out[0] = sqrtf(acc[0]) + 1e-4f * acc[1];
}

extern "C" void kernel_launch(void* const* d_in, const int* in_sizes, int n_in,
                              void* d_out, int out_size, void* d_ws, size_t ws_size,
                              hipStream_t stream) {
    const float* X    = (const float*)d_in[0];
    const float* W0   = (const float*)d_in[1];
    const float* W1   = (const float*)d_in[2];
    const float* v00  = (const float*)d_in[3];
    const float* v01  = (const float*)d_in[4];
    const float* pv00 = (const float*)d_in[5];
    const float* pv01 = (const float*)d_in[6];
    const int* rows   = (const int*)d_in[7];
    const int* cols   = (const int*)d_in[8];
    const int* prows  = (const int*)d_in[9];
    const int* pcols  = (const int*)d_in[10];

    float* out  = (float*)d_out;
    float* Henc = out + 1;                                  // N x 64 (misaligned base)
    float* Xrec = out + 1 + (size_t)N_NODES * 64;           // N x 256 (misaligned base)

    // scratch in dead X_ region [6400001, 32000001):
    ushort* bufAh  = (ushort*)(out + 6400004);              // N x 128 bf16
    ushort* Sh     = (ushort*)(out + 6400004);              // N x 64 bf16 (after bufAh dead)
    int*    ccol   = (int*)(out + 12800004);                // 4.8M int (padded CSR)
    int2*   eg     = (int2*)(out + 17600004);               // 4.8M int2
    ushort* HencB  = (ushort*)(out + 27200004);             // N x 64 bf16
    int*    deg    = (int*)(out + 28800004);                // 2N
    int*    cur    = deg + TOT;                             // 2N

    float* ws   = (float*)d_ws;
    float* bufB = ws;                                       // N x 128 fp32 / bf16
    ushort* bufBh = (ushort*)bufB;
    float* f1   = bufB + (size_t)N_NODES * 128;
    float* f2   = f1 + N_NODES;
    float* pf1  = f2 + N_NODES;
    float* pf2  = pf1 + N_NODES;
    float* acc  = pf2 + N_NODES;                            // 4
    ushort* B1cm = (ushort*)(acc + 4);                      // 128 x 264
    ushort* B5cm = B1cm + 128 * 264;                        // 64 x 136
    ushort* B7cm = B5cm + 64 * 136;                         // 128 x 72
    ushort* B8cm = B7cm + 128 * 72;                         // 256 x 136
    int*   rp   = (int*)(B8cm + 256 * 136);                 // 2N+1
    int*   bsum = rp + TOT + 1;                             // SCAN_NB
    float* partial = (float*)(bsum + SCAN_NB);              // cdiv(n,128)

    const int n = N_NODES;
    const int EG = cdiv(N_EDGES, 256);
    const int EG2 = cdiv(2 * (long)N_EDGES, 256);

    // 0. weight prep (single race-free kernel)
    prep_all_kernel<<<cdiv(81920, 256), 256, 0, stream>>>(W0, W1, B1cm, B5cm, B7cm, B8cm);

    // 1. H1 = X @ W0 -> bufAh (bf16), MFMA
    gemm_mfma<256, 128, true, 2, false, false><<<cdiv(n, 128), 256, 0, stream>>>(
        X, B1cm, bufAh, nullptr, nullptr, nullptr, n);

    // zero deg+cur and acc
    hipMemsetAsync(deg, 0, 2 * (size_t)TOT * sizeof(int), stream);
    hipMemsetAsync(acc, 0, 4 * sizeof(float), stream);

    // 2. attention feature dots
    attn_f4_kernel<<<cdiv(n, 4), 256, 0, stream>>>(bufAh, v00, v01, pv00, pv01,
                                                   f1, f2, pf1, pf2);

    // 3. padded interleaved CSR (bucket = 2r+adj) + pre-scaled softmax weights
    hist2_kernel<<<EG2, 256, 0, stream>>>(rows, prows, deg);
    scan1_kernel<<<SCAN_NB, 256, 0, stream>>>(deg, bsum);
    scan2_kernel<<<1, 64, 0, stream>>>(bsum);
    scan3_kernel<<<SCAN_NB, 256, 0, stream>>>(deg, bsum, rp);
    for (int p = 0; p < 4; ++p)
        scatter_bucket_kernel<<<EG, 256, 0, stream>>>(rows, cols, 0,
                                                      p * RPB, (p + 1) * RPB,
                                                      rp, cur, ccol);
    for (int p = 0; p < 4; ++p)
        scatter_bucket_kernel<<<EG, 256, 0, stream>>>(prows, pcols, 1,
                                                      p * RPB, (p + 1) * RPB,
                                                      rp, cur, ccol);
    edgeval_kernel<<<cdiv(TOT, 16), 256, 0, stream>>>(rp, deg, ccol,
                                                      f1, f2, pf1, pf2, eg);

    // 4. encoder: bufB(fp32) = elu(spmm)
    spmm_fused_kernel<<<n / 4, 256, 0, stream>>>(rp, eg, bufAh, bufB);

    // 5. Henc = bufB @ W1 -> d_out (fp32) + HencB (bf16), MFMA
    gemm_mfma<128, 64, true, 3, false, false><<<cdiv(n, 128), 256, 0, stream>>>(
        bufB, B5cm, Henc, HencB, nullptr, nullptr, n);

    // 6. decoder spmm on Henc (64-wide) -> Sh (bf16, bufAh region now dead)
    spmm64_fused_kernel<<<n / 4, 256, 0, stream>>>(rp, eg, HencB, Sh);

    // 7. D = elu(Sh @ W1T) -> bufBh (bf16), MFMA (bf16-A path)
    gemm_mfma<64, 128, false, 2, true, false><<<cdiv(n, 128), 256, 0, stream>>>(
        Sh, B7cm, bufBh, nullptr, nullptr, nullptr, n);

    // 8. X_ = bufBh @ W0T -> Xrec + fused loss partials, MFMA
    gemm_mfma<128, 256, false, 0, false, true><<<cdiv(n, 128), 256, 0, stream>>>(
        bufBh, B8cm, Xrec, nullptr, X, partial, n);

    // 9. loss (both weight norms accumulate into acc[1])
    partial_reduce_kernel<<<1, 256, 0, stream>>>(partial, cdiv(n, 128), acc + 0);
    sq_reduce_kernel<<<16, 256, 0, stream>>>(W0, acc + 1, 256 * 128);
    sq_reduce_kernel<<<4, 256, 0, stream>>>(W1, acc + 1, 128 * 64);
    finalize_kernel<<<1, 1, 0, stream>>>(acc, out);
}

// Round 17
// 745.350 us; speedup vs baseline: 1.2561x; 1.0656x over previous
//
#include <hip/hip_runtime.h>
#include <math.h>

#define N_NODES 100000
#define N_EDGES 1600000
#define TOT (2 * N_NODES)            // CSR buckets: 2*row + adj
#define SCAN_NB 256
#define SCAN_CH 4                    // 256*256*4 = 262144 >= 2N+1

static inline int cdiv(long a, long b) { return (int)((a + b - 1) / b); }

typedef unsigned int uint;
typedef unsigned short ushort;
typedef __attribute__((ext_vector_type(8))) short short8v;   // 8 bf16 (4 VGPR)
typedef __attribute__((ext_vector_type(4))) float f32x4;

__device__ inline float bf2f(uint u) { return __uint_as_float(u << 16); }
__device__ inline ushort f2bf(float f) {
    uint u = __float_as_uint(f);
    uint r = ((u >> 16) & 1u) + 0x7fffu;   // RNE
    return (ushort)((u + r) >> 16);
}

// ---------------- MFMA bf16 GEMM: C[i,m] = sum_k A[i,k]*B[k,m] --------------
// ATTN (M==128 only): fused attention feature dots from fp32 accumulators.
template <int K, int M, bool AF32, int OUT, bool ELU, bool LOSS, bool ATTN>
__global__ __launch_bounds__(256) void gemm_mfma(const void* __restrict__ Av,
                                                 const ushort* __restrict__ Bcm,
                                                 void* __restrict__ Cv,
                                                 void* __restrict__ Cv2,
                                                 const float* __restrict__ Xref,
                                                 float* __restrict__ partial,
                                                 const float* __restrict__ va,
                                                 const float* __restrict__ vb,
                                                 const float* __restrict__ pva,
                                                 const float* __restrict__ pvb,
                                                 float* __restrict__ f1,
                                                 float* __restrict__ f2,
                                                 float* __restrict__ pf1,
                                                 float* __restrict__ pf2,
                                                 int nrows) {
    constexpr int BM = 128;
    constexpr int KP = K + 8;
    constexpr int NCT = M / 16;
    __shared__ ushort Blds[M * KP];
    __shared__ ushort Alds[BM * 32];
    const int w = threadIdx.x >> 6;
    const int l = threadIdx.x & 63;
    const int rowg = l & 15;
    const int kg = l >> 4;
    const int rbase = blockIdx.x * BM;
    {
        const uint4* src = reinterpret_cast<const uint4*>(Bcm);
        uint4* dst = reinterpret_cast<uint4*>(Blds);
        const int total = M * KP / 8;
        for (int i = threadIdx.x; i < total; i += 256) dst[i] = src[i];
    }
    f32x4 acc[2][NCT] = {};
    for (int k0 = 0; k0 < K; k0 += 32) {
        __syncthreads();
        int r = threadIdx.x >> 1;
        int kk = (threadIdx.x & 1) * 16;
        int rg = min(rbase + r, nrows - 1);
        if (AF32) {
            const float* A = (const float*)Av;
            const float4* src = reinterpret_cast<const float4*>(A + (size_t)rg * K + k0 + kk);
            ushort* dst = &Alds[r * 32 + kk];
#pragma unroll
            for (int q = 0; q < 4; ++q) {
                float4 v = src[q];
                dst[4 * q + 0] = f2bf(v.x); dst[4 * q + 1] = f2bf(v.y);
                dst[4 * q + 2] = f2bf(v.z); dst[4 * q + 3] = f2bf(v.w);
            }
        } else {
            const ushort* A = (const ushort*)Av;
            const uint4* src = reinterpret_cast<const uint4*>(A + (size_t)rg * K + k0 + kk);
            uint4* dst = reinterpret_cast<uint4*>(&Alds[r * 32 + kk]);
            dst[0] = src[0];
            dst[1] = src[1];
        }
        __syncthreads();
#pragma unroll
        for (int rt = 0; rt < 2; ++rt) {
            short8v af = *reinterpret_cast<const short8v*>(
                &Alds[(w * 32 + rt * 16 + rowg) * 32 + kg * 8]);
#pragma unroll
            for (int ct = 0; ct < NCT; ++ct) {
                short8v bf = *reinterpret_cast<const short8v*>(
                    &Blds[(ct * 16 + rowg) * KP + k0 + kg * 8]);
                acc[rt][ct] = __builtin_amdgcn_mfma_f32_16x16x32_bf16(
                    af, bf, acc[rt][ct], 0, 0, 0);
            }
        }
    }
    float lsum = 0.f;
#pragma unroll
    for (int rt = 0; rt < 2; ++rt) {
#pragma unroll
        for (int q = 0; q < 4; ++q) {
            int r = rbase + w * 32 + rt * 16 + kg * 4 + q;
            if (r >= nrows) continue;
#pragma unroll
            for (int ct = 0; ct < NCT; ++ct) {
                float o = acc[rt][ct][q];
                if (ELU) o = o > 0.f ? o : expm1f(o);
                int col = ct * 16 + rowg;
                if (OUT == 0 || OUT == 3) ((float*)Cv)[(size_t)r * M + col] = o;
                if (OUT == 2) ((ushort*)Cv)[(size_t)r * M + col] = f2bf(o);
                if (OUT == 3) ((ushort*)Cv2)[(size_t)r * M + col] = f2bf(o);
                if (LOSS) {
                    float d = o - Xref[(size_t)r * 256 + col];
                    lsum += d * d;
                }
            }
        }
    }
    if (ATTN) {
        // per-lane column set {ct*16+rowg} is fixed -> cache the 4 vectors
        float var[NCT], vbr[NCT], pvar[NCT], pvbr[NCT];
#pragma unroll
        for (int ct = 0; ct < NCT; ++ct) {
            int col = ct * 16 + rowg;
            var[ct] = va[col]; vbr[ct] = vb[col];
            pvar[ct] = pva[col]; pvbr[ct] = pvb[col];
        }
#pragma unroll
        for (int rt = 0; rt < 2; ++rt) {
#pragma unroll
            for (int q = 0; q < 4; ++q) {
                int r = rbase + w * 32 + rt * 16 + kg * 4 + q;
                float da = 0.f, db = 0.f, dpa = 0.f, dpb = 0.f;
#pragma unroll
                for (int ct = 0; ct < NCT; ++ct) {
                    float o = acc[rt][ct][q];
                    da += o * var[ct]; db += o * vbr[ct];
                    dpa += o * pvar[ct]; dpb += o * pvbr[ct];
                }
#pragma unroll
                for (int m = 1; m < 16; m <<= 1) {
                    da += __shfl_xor(da, m); db += __shfl_xor(db, m);
                    dpa += __shfl_xor(dpa, m); dpb += __shfl_xor(dpb, m);
                }
                if (rowg == 0 && r < nrows) {
                    f1[r] = da; f2[r] = db; pf1[r] = dpa; pf2[r] = dpb;
                }
            }
        }
    }
    if (LOSS) {
        __shared__ float smRed[4];
#pragma unroll
        for (int off = 32; off > 0; off >>= 1) lsum += __shfl_down(lsum, off);
        __syncthreads();
        if (l == 0) smRed[w] = lsum;
        __syncthreads();
        if (threadIdx.x == 0)
            partial[blockIdx.x] = smRed[0] + smRed[1] + smRed[2] + smRed[3];
    }
}

// ---------------- weight prep: all 4 bf16 col-major padded B's, one kernel --
__global__ __launch_bounds__(256) void prep_all_kernel(const float* __restrict__ W0,
                                                       const float* __restrict__ W1,
                                                       ushort* __restrict__ B1,
                                                       ushort* __restrict__ B5,
                                                       ushort* __restrict__ B7,
                                                       ushort* __restrict__ B8) {
    int i = blockIdx.x * 256 + threadIdx.x;
    if (i < 32768) {                            // B1[m][k] = W0[k][m], K=256 M=128
        int k = i / 128, m = i - k * 128;
        B1[m * 264 + k] = f2bf(W0[i]);
    } else if (i < 65536) {                     // B8[m][k] = W0[m][k], K=128 M=256
        int j = i - 32768;
        int m = j / 128, k = j - m * 128;
        B8[m * 136 + k] = f2bf(W0[j]);
    } else if (i < 73728) {                     // B5[m][k] = W1[k][m], K=128 M=64
        int j = i - 65536;
        int k = j / 64, m = j - k * 64;
        B5[m * 136 + k] = f2bf(W1[j]);
    } else if (i < 81920) {                     // B7[m][k] = W1[m][k], K=64 M=128
        int j = i - 73728;
        int m = j / 64, k = j - m * 64;
        B7[m * 72 + k] = f2bf(W1[j]);
    }
}

// ---------------- CSR build: bucket = 2*row + adj, rows padded to x8 --------
__global__ __launch_bounds__(256) void hist2_kernel(const int* __restrict__ rows,
                                                    const int* __restrict__ prows,
                                                    int* __restrict__ deg) {
    int e = blockIdx.x * 256 + threadIdx.x;
    if (e >= 2 * N_EDGES) return;
    int b = e < N_EDGES ? rows[e] * 2 : prows[e - N_EDGES] * 2 + 1;
    atomicAdd(&deg[b], 1);
}

__device__ inline int pad8(int d) { return (d + 7) & ~7; }

__global__ __launch_bounds__(256) void scan1_kernel(const int* __restrict__ deg,
                                                    int* __restrict__ bsum) {
    __shared__ int sm[256];
    int base = (blockIdx.x * 256 + threadIdx.x) * SCAN_CH;
    int s = 0;
#pragma unroll
    for (int i = 0; i < SCAN_CH; ++i) {
        int idx = base + i;
        if (idx < TOT) s += pad8(deg[idx]);
    }
    sm[threadIdx.x] = s;
    __syncthreads();
    for (int off = 128; off > 0; off >>= 1) {
        if (threadIdx.x < off) sm[threadIdx.x] += sm[threadIdx.x + off];
        __syncthreads();
    }
    if (threadIdx.x == 0) bsum[blockIdx.x] = sm[0];
}

// scan3 with inlined bsum prefix (no scan2 kernel)
__global__ __launch_bounds__(256) void scan3_kernel(const int* __restrict__ deg,
                                                    const int* __restrict__ bsum,
                                                    int* __restrict__ rp) {
    __shared__ int sm[256];
    __shared__ int base0;
    if (threadIdx.x == 0) {
        int run = 0;
        for (int i = 0; i < blockIdx.x; ++i) run += bsum[i];
        base0 = run;
    }
    int base = (blockIdx.x * 256 + threadIdx.x) * SCAN_CH;
    int s = 0;
#pragma unroll
    for (int i = 0; i < SCAN_CH; ++i) {
        int idx = base + i;
        if (idx < TOT) s += pad8(deg[idx]);
    }
    sm[threadIdx.x] = s;
    __syncthreads();
    if (threadIdx.x == 0) {
        int run = base0;
        for (int t = 0; t < 256; ++t) { int tmp = sm[t]; sm[t] = run; run += tmp; }
    }
    __syncthreads();
    int off = sm[threadIdx.x];
#pragma unroll
    for (int i = 0; i < SCAN_CH; ++i) {
        int idx = base + i;
        if (idx < TOT) { rp[idx] = off; off += pad8(deg[idx]); }
        else if (idx == TOT) rp[idx] = off;
    }
}

// single-pass scatter per list: 4B column ids only
__global__ __launch_bounds__(256) void scatter_kernel(const int* __restrict__ rlist,
                                                      const int* __restrict__ clist,
                                                      int adj,
                                                      const int* __restrict__ rp,
                                                      int* __restrict__ cur,
                                                      int* __restrict__ ccol) {
    int e = blockIdx.x * 256 + threadIdx.x;
    if (e >= N_EDGES) return;
    int b = rlist[e] * 2 + adj;
    int pos = rp[b] + atomicAdd(&cur[b], 1);
    ccol[pos] = clist[e];
}

// ---------------- edge weights: pre-normalized+scaled; pad slots = {0,0} ----
__global__ __launch_bounds__(256) void edgeval_kernel(const int* __restrict__ rp,
                                                      const int* __restrict__ deg,
                                                      const int* __restrict__ ccol,
                                                      const float* __restrict__ f1,
                                                      const float* __restrict__ f2,
                                                      const float* __restrict__ pf1,
                                                      const float* __restrict__ pf2,
                                                      int2* __restrict__ eg) {
    int b = blockIdx.x * 16 + (threadIdx.x >> 4);
    int sl = threadIdx.x & 15;
    int adj = b & 1, r = b >> 1;
    float f1r = adj ? pf1[r] : f1[r];
    const float* f2t = adj ? pf2 : f2;
    float scale = adj ? 0.8f : 0.2f;
    int j0 = rp[b];
    int realend = j0 + deg[b];
    int pend = rp[b + 1];
    float s = 0.f;
    for (int j = j0 + sl; j < realend; j += 16)
        s += __expf(f1r + f2t[ccol[j]]);
#pragma unroll
    for (int off = 8; off > 0; off >>= 1) s += __shfl_xor(s, off);
    float inv = s > 0.f ? scale / s : 0.f;
    for (int j = j0 + sl; j < pend; j += 16) {
        if (j < realend) {
            int c = ccol[j];
            float wv = __expf(f1r + f2t[c]) * inv;
            eg[j] = make_int2(c, __float_as_int(wv));
        } else {
            eg[j] = make_int2(0, 0);
        }
    }
}

// ---------------- fused SpMM, unified row stream, 2-stage pipeline ----------
#define SPU 8
// encoder: gathers 128-wide bf16 H, emits bf16 (packed uint per lane)
__global__ __launch_bounds__(256) void spmm_fused_kernel(const int* __restrict__ rp,
                                                         const int2* __restrict__ eg,
                                                         const ushort* __restrict__ Hb,
                                                         uint* __restrict__ outh) {
    int r = blockIdx.x * 4 + (threadIdx.x >> 6);
    int lane = threadIdx.x & 63;
    const uint* Hu = reinterpret_cast<const uint*>(Hb);
    float a0 = 0.f, a1 = 0.f;
    int j = rp[2 * r], E = rp[2 * r + 2];
    if (j < E) {
        int2 d[SPU]; uint h[SPU];
#pragma unroll
        for (int u = 0; u < SPU; ++u) d[u] = eg[j + u];
#pragma unroll
        for (int u = 0; u < SPU; ++u) h[u] = Hu[(uint)d[u].x * 64u + lane];
        j += SPU;
        for (; j < E; j += SPU) {
            int2 dn[SPU]; uint hn[SPU];
#pragma unroll
            for (int u = 0; u < SPU; ++u) dn[u] = eg[j + u];
#pragma unroll
            for (int u = 0; u < SPU; ++u) hn[u] = Hu[(uint)dn[u].x * 64u + lane];
#pragma unroll
            for (int u = 0; u < SPU; ++u) {
                float v = __int_as_float(d[u].y);
                a0 += v * bf2f(h[u] & 0xffffu);
                a1 += v * bf2f(h[u] >> 16);
            }
#pragma unroll
            for (int u = 0; u < SPU; ++u) { d[u] = dn[u]; h[u] = hn[u]; }
        }
#pragma unroll
        for (int u = 0; u < SPU; ++u) {
            float v = __int_as_float(d[u].y);
            a0 += v * bf2f(h[u] & 0xffffu);
            a1 += v * bf2f(h[u] >> 16);
        }
    }
    float o0 = a0 > 0.f ? a0 : expm1f(a0);
    float o1 = a1 > 0.f ? a1 : expm1f(a1);
    outh[(size_t)r * 64 + lane] = (uint)f2bf(o0) | ((uint)f2bf(o1) << 16);
}

// decoder: gathers 64-wide bf16 Henc, emits bf16 S
__global__ __launch_bounds__(256) void spmm64_fused_kernel(const int* __restrict__ rp,
                                                           const int2* __restrict__ eg,
                                                           const ushort* __restrict__ Hb,
                                                           ushort* __restrict__ Sh) {
    int r = blockIdx.x * 4 + (threadIdx.x >> 6);
    int lane = threadIdx.x & 63;
    float a = 0.f;
    int j = rp[2 * r], E = rp[2 * r + 2];
    if (j < E) {
        int2 d[SPU]; ushort h[SPU];
#pragma unroll
        for (int u = 0; u < SPU; ++u) d[u] = eg[j + u];
#pragma unroll
        for (int u = 0; u < SPU; ++u) h[u] = Hb[(uint)d[u].x * 64u + lane];
        j += SPU;
        for (; j < E; j += SPU) {
            int2 dn[SPU]; ushort hn[SPU];
#pragma unroll
            for (int u = 0; u < SPU; ++u) dn[u] = eg[j + u];
#pragma unroll
            for (int u = 0; u < SPU; ++u) hn[u] = Hb[(uint)dn[u].x * 64u + lane];
#pragma unroll
            for (int u = 0; u < SPU; ++u)
                a += __int_as_float(d[u].y) * bf2f((uint)h[u]);
#pragma unroll
            for (int u = 0; u < SPU; ++u) { d[u] = dn[u]; h[u] = hn[u]; }
        }
#pragma unroll
        for (int u = 0; u < SPU; ++u)
            a += __int_as_float(d[u].y) * bf2f((uint)h[u]);
    }
    Sh[(size_t)r * 64 + lane] = f2bf(a);
}

// ---------------- reductions -----------------------------------------------
// both weight norms in one kernel (flat index over W0 then W1)
__global__ __launch_bounds__(256) void sqw_reduce_kernel(const float* __restrict__ W0,
                                                         const float* __restrict__ W1,
                                                         float* __restrict__ acc) {
    __shared__ float sm[4];
    float s = 0.f;
    for (int i = blockIdx.x * 256 + threadIdx.x; i < 40960; i += gridDim.x * 256) {
        float d = i < 32768 ? W0[i] : W1[i - 32768];
        s += d * d;
    }
#pragma unroll
    for (int off = 32; off > 0; off >>= 1) s += __shfl_down(s, off);
    int lane = threadIdx.x & 63, w = threadIdx.x >> 6;
    if (lane == 0) sm[w] = s;
    __syncthreads();
    if (threadIdx.x == 0) atomicAdd(acc, sm[0] + sm[1] + sm[2] + sm[3]);
}

__global__ __launch_bounds__(256) void partial_reduce_kernel(const float* __restrict__ p,
                                                             int n, float* __restrict__ acc) {
    __shared__ float sm[4];
    float s = 0.f;
    for (int i = threadIdx.x; i < n; i += 256) s += p[i];
#pragma unroll
    for (int off = 32; off > 0; off >>= 1) s += __shfl_down(s, off);
    int lane = threadIdx.x & 63, w = threadIdx.x >> 6;
    if (lane == 0) sm[w] = s;
    __syncthreads();
    if (threadIdx.x == 0) atomicAdd(acc, sm[0] + sm[1] + sm[2] + sm[3]);
}

__global__ void finalize_kernel(const float* __restrict__ acc, float* __restrict__ out) {
    out[0] = sqrtf(acc[0]) + 1e-4f * acc[1];
}

extern "C" void kernel_launch(void* const* d_in, const int* in_sizes, int n_in,
                              void* d_out, int out_size, void* d_ws, size_t ws_size,
                              hipStream_t stream) {
    const float* X    = (const float*)d_in[0];
    const float* W0   = (const float*)d_in[1];
    const float* W1   = (const float*)d_in[2];
    const float* v00  = (const float*)d_in[3];
    const float* v01  = (const float*)d_in[4];
    const float* pv00 = (const float*)d_in[5];
    const float* pv01 = (const float*)d_in[6];
    const int* rows   = (const int*)d_in[7];
    const int* cols   = (const int*)d_in[8];
    const int* prows  = (const int*)d_in[9];
    const int* pcols  = (const int*)d_in[10];

    float* out  = (float*)d_out;
    float* Henc = out + 1;                                  // N x 64 (misaligned base)
    float* Xrec = out + 1 + (size_t)N_NODES * 64;           // N x 256 (misaligned base)

    // scratch in dead X_ region [6400001, 32000001):
    ushort* bufAh  = (ushort*)(out + 6400004);              // N x 128 bf16
    ushort* Sh     = (ushort*)(out + 6400004);              // N x 64 bf16 (after bufAh dead)
    int*    ccol   = (int*)(out + 12800004);                // 4.8M int (padded CSR)
    int2*   eg     = (int2*)(out + 17600004);               // 4.8M int2
    ushort* HencB  = (ushort*)(out + 27200004);             // N x 64 bf16
    int*    deg    = (int*)(out + 28800004);                // 2N
    int*    cur    = deg + TOT;                             // 2N

    float* ws   = (float*)d_ws;
    ushort* bufBh = (ushort*)ws;                            // N x 128 bf16
    float* f1   = ws + (size_t)N_NODES * 128;
    float* f2   = f1 + N_NODES;
    float* pf1  = f2 + N_NODES;
    float* pf2  = pf1 + N_NODES;
    float* acc  = pf2 + N_NODES;                            // 4
    ushort* B1cm = (ushort*)(acc + 4);                      // 128 x 264
    ushort* B5cm = B1cm + 128 * 264;                        // 64 x 136
    ushort* B7cm = B5cm + 64 * 136;                         // 128 x 72
    ushort* B8cm = B7cm + 128 * 72;                         // 256 x 136
    int*   rp   = (int*)(B8cm + 256 * 136);                 // 2N+1
    int*   bsum = rp + TOT + 1;                             // SCAN_NB
    float* partial = (float*)(bsum + SCAN_NB);              // cdiv(n,128)

    const int n = N_NODES;
    const int EG = cdiv(N_EDGES, 256);
    const int EG2 = cdiv(2 * (long)N_EDGES, 256);

    // 0. weight prep
    prep_all_kernel<<<cdiv(81920, 256), 256, 0, stream>>>(W0, W1, B1cm, B5cm, B7cm, B8cm);

    // 1. H1 = X @ W0 -> bufAh (bf16) + fused attention dots, MFMA
    gemm_mfma<256, 128, true, 2, false, false, true><<<cdiv(n, 128), 256, 0, stream>>>(
        X, B1cm, bufAh, nullptr, nullptr, nullptr,
        v00, v01, pv00, pv01, f1, f2, pf1, pf2, n);

    // zero deg+cur and acc
    hipMemsetAsync(deg, 0, 2 * (size_t)TOT * sizeof(int), stream);
    hipMemsetAsync(acc, 0, 4 * sizeof(float), stream);

    // 2. padded interleaved CSR (bucket = 2r+adj) + pre-scaled softmax weights
    hist2_kernel<<<EG2, 256, 0, stream>>>(rows, prows, deg);
    scan1_kernel<<<SCAN_NB, 256, 0, stream>>>(deg, bsum);
    scan3_kernel<<<SCAN_NB, 256, 0, stream>>>(deg, bsum, rp);
    scatter_kernel<<<EG, 256, 0, stream>>>(rows, cols, 0, rp, cur, ccol);
    scatter_kernel<<<EG, 256, 0, stream>>>(prows, pcols, 1, rp, cur, ccol);
    edgeval_kernel<<<cdiv(TOT, 16), 256, 0, stream>>>(rp, deg, ccol,
                                                      f1, f2, pf1, pf2, eg);

    // 3. encoder: bufBh(bf16) = elu(spmm)
    spmm_fused_kernel<<<n / 4, 256, 0, stream>>>(rp, eg, bufAh, (uint*)bufBh);

    // 4. Henc = bufBh @ W1 -> d_out (fp32) + HencB (bf16), MFMA (bf16-A)
    gemm_mfma<128, 64, false, 3, false, false, false><<<cdiv(n, 128), 256, 0, stream>>>(
        bufBh, B5cm, Henc, HencB, nullptr, nullptr,
        nullptr, nullptr, nullptr, nullptr, nullptr, nullptr, nullptr, nullptr, n);

    // 5. decoder spmm on Henc (64-wide) -> Sh (bf16, bufAh region now dead)
    spmm64_fused_kernel<<<n / 4, 256, 0, stream>>>(rp, eg, HencB, Sh);

    // 6. D = elu(Sh @ W1T) -> bufBh (bf16), MFMA (bf16-A)
    gemm_mfma<64, 128, false, 2, true, false, false><<<cdiv(n, 128), 256, 0, stream>>>(
        Sh, B7cm, bufBh, nullptr, nullptr, nullptr,
        nullptr, nullptr, nullptr, nullptr, nullptr, nullptr, nullptr, nullptr, n);

    // 7. X_ = bufBh @ W0T -> Xrec + fused loss partials, MFMA
    gemm_mfma<128, 256, false, 0, false, true, false><<<cdiv(n, 128), 256, 0, stream>>>(
        bufBh, B8cm, Xrec, nullptr, X, partial,
        nullptr, nullptr, nullptr, nullptr, nullptr, nullptr, nullptr, nullptr, n);

    // 8. loss
    partial_reduce_kernel<<<1, 256, 0, stream>>>(partial, cdiv(n, 128), acc + 0);
    sqw_reduce_kernel<<<20, 256, 0, stream>>>(W0, W1, acc + 1);
    finalize_kernel<<<1, 1, 0, stream>>>(acc, out);
}